// Round 2
// 575.696 us; speedup vs baseline: 1.0029x; 1.0029x over previous
//
#include <hip/hip_runtime.h>
#include <hip/hip_bf16.h>
#include <stdint.h>

#define D_MODEL 768
#define N_HEAD 12
#define D_HEAD 64
#define BATCH 4
#define SEQ 1024
#define HB 48
#define PROJ_ELEMS (BATCH * SEQ * D_MODEL)   // 3145728

typedef __attribute__((ext_vector_type(8))) short bf8_t;   // 8 bf16 = one MFMA A/B frag
typedef __attribute__((ext_vector_type(4))) float f4_t;    // 4 fp32 = one MFMA C/D frag

__device__ inline unsigned short f2b(float f) {           // RNE float->bf16
    union { float f; unsigned u; } v; v.f = f;
    unsigned r = v.u + 0x7FFFu + ((v.u >> 16) & 1u);
    return (unsigned short)(r >> 16);
}

// ---------------------------------------------------------------------------
// fp32 -> bf16 bulk convert (weights only now; z picks one of 4 tensors)
// ---------------------------------------------------------------------------
__global__ __launch_bounds__(256) void cvt_k(
    const float* __restrict__ s0, const float* __restrict__ s1,
    const float* __restrict__ s2, const float* __restrict__ s3,
    unsigned short* __restrict__ d0, unsigned short* __restrict__ d1,
    unsigned short* __restrict__ d2, unsigned short* __restrict__ d3, int n)
{
    const int z = blockIdx.z;
    const float* s = (z == 0) ? s0 : (z == 1) ? s1 : (z == 2) ? s2 : s3;
    unsigned short* d = (z == 0) ? d0 : (z == 1) ? d1 : (z == 2) ? d2 : d3;
    int i = (blockIdx.x * 256 + threadIdx.x) * 4;
    if (i >= n) return;
    float4 v = *(const float4*)(s + i);
    ushort4 o;
    o.x = f2b(v.x); o.y = f2b(v.y); o.z = f2b(v.z); o.w = f2b(v.w);
    *(ushort4*)(d + i) = o;
}

// ---------------------------------------------------------------------------
// QKV projection: Y = X(fp32, cvt inline) * W^T + bias, bf16 MFMA, 128x128
// tile, BK=64. Output head-split bf16: out[((h*4+b)*1024 + l)*64 + dh]
// XCD-chunked swizzle: 192 wg/z, 8 XCDs x 24 -> each XCD reuses 4 X-panels.
// ---------------------------------------------------------------------------
__global__ __launch_bounds__(256) void proj_mfma(
    const float* __restrict__ qf, const float* __restrict__ kf,
    const float* __restrict__ vf,
    const unsigned short* __restrict__ wqb, const unsigned short* __restrict__ wkb,
    const unsigned short* __restrict__ wvb,
    const float* __restrict__ bq, const float* __restrict__ bk, const float* __restrict__ bv,
    unsigned short* __restrict__ qh, unsigned short* __restrict__ kh,
    unsigned short* __restrict__ vh)
{
    const int z = blockIdx.z;
    const float* X = (z == 0) ? qf : (z == 1) ? kf : vf;
    const unsigned short* W = (z == 0) ? wqb : (z == 1) ? wkb : wvb;
    const float* bias = (z == 0) ? bq : (z == 1) ? bk : bv;
    unsigned short* Out = (z == 0) ? qh : (z == 1) ? kh : vh;

    const int orig = blockIdx.y * 6 + blockIdx.x;       // 0..191
    const int swz  = (orig & 7) * 24 + (orig >> 3);     // bijective (192 = 8*24)
    const int m0 = (swz / 6) * 128;
    const int n0 = (swz % 6) * 128;

    __shared__ alignas(16) unsigned short As[128 * 72];   // row stride 72 shorts
    __shared__ alignas(16) unsigned short Bs[128 * 72];

    const int tid = threadIdx.x;
    const int wave = tid >> 6, lane = tid & 63;
    const int quad = lane >> 4, lq = lane & 15;
    const int wr = wave >> 1, wc = wave & 1;   // wave's 64x64 quadrant

    f4_t acc[4][4];
    #pragma unroll
    for (int i = 0; i < 4; ++i)
        #pragma unroll
        for (int j = 0; j < 4; ++j)
            #pragma unroll
            for (int r = 0; r < 4; ++r) acc[i][j][r] = 0.0f;

    for (int k0 = 0; k0 < D_MODEL; k0 += 64) {
        #pragma unroll
        for (int i = 0; i < 4; ++i) {
            int c = tid + 256 * i;            // 1024 16B-chunks per tile
            int row = c >> 3, off = (c & 7) * 8;
            const float* src = X + (size_t)(m0 + row) * D_MODEL + k0 + off;
            float4 u0 = *(const float4*)src;
            float4 u1 = *(const float4*)(src + 4);
            union { unsigned short u[8]; bf8_t v; } t;
            t.u[0] = f2b(u0.x); t.u[1] = f2b(u0.y); t.u[2] = f2b(u0.z); t.u[3] = f2b(u0.w);
            t.u[4] = f2b(u1.x); t.u[5] = f2b(u1.y); t.u[6] = f2b(u1.z); t.u[7] = f2b(u1.w);
            *(bf8_t*)(As + row * 72 + off) = t.v;
            *(bf8_t*)(Bs + row * 72 + off) =
                *(const bf8_t*)(W + (size_t)(n0 + row) * D_MODEL + k0 + off);
        }
        __syncthreads();
        #pragma unroll
        for (int ks = 0; ks < 2; ++ks) {
            bf8_t af[4], bfr[4];
            #pragma unroll
            for (int i = 0; i < 4; ++i)
                af[i] = *(const bf8_t*)(As + (wr * 64 + i * 16 + lq) * 72 + ks * 32 + quad * 8);
            #pragma unroll
            for (int j = 0; j < 4; ++j)
                bfr[j] = *(const bf8_t*)(Bs + (wc * 64 + j * 16 + lq) * 72 + ks * 32 + quad * 8);
            #pragma unroll
            for (int i = 0; i < 4; ++i)
                #pragma unroll
                for (int j = 0; j < 4; ++j)
                    acc[i][j] = __builtin_amdgcn_mfma_f32_16x16x32_bf16(af[i], bfr[j], acc[i][j], 0, 0, 0);
        }
        __syncthreads();
    }

    const int bb = m0 >> 10;
    #pragma unroll
    for (int j = 0; j < 4; ++j) {
        int col = n0 + wc * 64 + j * 16 + lq;
        float bv_ = bias[col];
        int h = col >> 6, dh = col & 63;
        #pragma unroll
        for (int i = 0; i < 4; ++i) {
            #pragma unroll
            for (int r = 0; r < 4; ++r) {
                int m = m0 + wr * 64 + i * 16 + quad * 4 + r;
                int l = m & 1023;
                Out[(((size_t)(h * BATCH + bb) * SEQ + l) << 6) + dh] = f2b(acc[i][j][r] + bv_);
            }
        }
    }
}

// ---------------------------------------------------------------------------
// Transpose V per (hb, t-tile): vT[hb][dh][t] from vh[hb][t][dh]
// ---------------------------------------------------------------------------
__global__ __launch_bounds__(256) void vtrans(
    const unsigned short* __restrict__ vh, unsigned short* __restrict__ vT)
{
    const int hb = blockIdx.y, tt = blockIdx.x;
    __shared__ alignas(16) unsigned short s[64 * 72];
    const int tid = threadIdx.x;
    #pragma unroll
    for (int i = 0; i < 2; ++i) {
        int c = tid + 256 * i;
        int t = c >> 3, off = (c & 7) * 8;
        *(bf8_t*)(s + t * 72 + off) =
            *(const bf8_t*)(vh + ((size_t)hb * SEQ + tt * 64 + t) * 64 + off);
    }
    __syncthreads();
    #pragma unroll
    for (int i = 0; i < 2; ++i) {
        int c = tid + 256 * i;
        int dh = c >> 3, toff = (c & 7) * 8;
        union { unsigned short u[8]; bf8_t v; } tmp;
        #pragma unroll
        for (int j = 0; j < 8; ++j) tmp.u[j] = s[(toff + j) * 72 + dh];
        *(bf8_t*)(vT + ((size_t)hb * 64 + dh) * SEQ + tt * 64 + toff) = tmp.v;
    }
}

// ---------------------------------------------------------------------------
// Fused loc + QK^T + mask -> UNNORMALIZED scores e = clip(loc)*exp(qk/8)
// written to fused[h][b][l][t] (fp32), plus deterministic per-row partial
// sums psum[(hb*SEQ+l)*16 + tblk]. No row max needed: |qk/8| <~ 2 so the
// un-shifted exp is safely in fp32 range. Softmax identity:
//   softmax(log(clip(loc)) + qk/8) = clip(loc)*exp(qk/8) / sum(...)
// Block: (b, l-tile 16, t-tile 64), loops all 12 heads; pl read ONCE.
// XCD-chunked swizzle so blocks sharing K/Q tiles land on the same L2.
// ---------------------------------------------------------------------------
__global__ __launch_bounds__(256) void attn_e(
    const unsigned short* __restrict__ qh, const unsigned short* __restrict__ kh,
    const float* __restrict__ pl, const int* __restrict__ mask,
    const float* __restrict__ wloc, const float* __restrict__ bloc,
    float* __restrict__ fused, float* __restrict__ psum)
{
    const int orig = (blockIdx.z * 64 + blockIdx.y) * 16 + blockIdx.x;  // 0..4095
    const int swz  = (orig & 7) * 512 + (orig >> 3);                    // 4096 = 8*512
    const int tblk = swz & 15;
    const int t0 = tblk * 64;
    const int l0 = ((swz >> 4) & 63) * 16;
    const int b  = swz >> 10;

    __shared__ alignas(16) float spl[16 * 324];            // [l][t*5], padded stride
    __shared__ alignas(16) unsigned short sq[16 * 72];
    __shared__ alignas(16) unsigned short sk[64 * 72];
    __shared__ float rsum[4][16];                          // [wave][row]

    const int tid = threadIdx.x;
    {   // cooperative pl tile load: 16 rows x 320 floats = 1280 float4, 5/thread
        int r = tid >> 4, c16 = tid & 15;
        const float* src = pl + (((size_t)(b * SEQ + l0 + r) * SEQ) + t0) * 5;
        float* dst = spl + r * 324;
        #pragma unroll
        for (int j = 0; j < 5; ++j) {
            int f4i = j * 16 + c16;            // 0..79
            *(float4*)(dst + f4i * 4) = *(const float4*)(src + f4i * 4);
        }
    }
    const int wave = tid >> 6, lane = tid & 63;
    const int quad = lane >> 4, lq = lane & 15;
    const int mk = mask[b * SEQ + t0 + wave * 16 + lq];

    for (int h = 0; h < N_HEAD; ++h) {
        const int hb = h * BATCH + b;
        if (tid < 128) {   // stage Q: 16 rows x 8 chunks
            int row = tid >> 3, off = (tid & 7) * 8;
            *(bf8_t*)(sq + row * 72 + off) =
                *(const bf8_t*)(qh + (((size_t)hb * SEQ) + l0 + row) * 64 + off);
        }
        #pragma unroll
        for (int i = 0; i < 2; ++i) {          // stage K: 64 rows x 8 chunks
            int c = tid + 256 * i;
            int r2 = c >> 3, o2 = (c & 7) * 8;
            *(bf8_t*)(sk + r2 * 72 + o2) =
                *(const bf8_t*)(kh + (((size_t)hb * SEQ) + t0 + r2) * 64 + o2);
        }
        __syncthreads();

        const float wl0 = wloc[h * 5 + 0], wl1 = wloc[h * 5 + 1], wl2 = wloc[h * 5 + 2];
        const float wl3 = wloc[h * 5 + 3], wl4 = wloc[h * 5 + 4];
        const float bl = bloc[h];

        bf8_t a0 = *(const bf8_t*)(sq + lq * 72 + quad * 8);
        bf8_t a1 = *(const bf8_t*)(sq + lq * 72 + 32 + quad * 8);
        bf8_t b0 = *(const bf8_t*)(sk + (wave * 16 + lq) * 72 + quad * 8);
        bf8_t b1 = *(const bf8_t*)(sk + (wave * 16 + lq) * 72 + 32 + quad * 8);
        f4_t acc = {0.f, 0.f, 0.f, 0.f};
        acc = __builtin_amdgcn_mfma_f32_16x16x32_bf16(a0, b0, acc, 0, 0, 0);
        acc = __builtin_amdgcn_mfma_f32_16x16x32_bf16(a1, b1, acc, 0, 0, 0);

        const int tt = wave * 16 + lq;          // tile-local t (0..63)
        float sr[4];
        #pragma unroll
        for (int r = 0; r < 4; ++r) {
            int ll = quad * 4 + r;              // tile-local l (0..15)
            const float* p5 = spl + ll * 324 + tt * 5;
            float loc = fmaf(wl0, p5[0], fmaf(wl1, p5[1], fmaf(wl2, p5[2],
                        fmaf(wl3, p5[3], fmaf(wl4, p5[4], bl)))));
            float e = mk ? 0.0f : fmaxf(loc, 1e-6f) * __expf(0.125f * acc[r]);
            fused[((size_t)hb * SEQ + l0 + ll) * SEQ + t0 + tt] = e;
            sr[r] = e;
        }
        // sum over the wave's 16 t (lq bits 0..3), per row
        #pragma unroll
        for (int o = 1; o < 16; o <<= 1) {
            sr[0] += __shfl_xor(sr[0], o, 64);
            sr[1] += __shfl_xor(sr[1], o, 64);
            sr[2] += __shfl_xor(sr[2], o, 64);
            sr[3] += __shfl_xor(sr[3], o, 64);
        }
        if (lq == 0) {
            #pragma unroll
            for (int r = 0; r < 4; ++r) rsum[wave][quad * 4 + r] = sr[r];
        }
        __syncthreads();                        // rsum visible; sq/sk reusable
        if (tid < 16)                           // combine 4 waves, write partial sum
            psum[((size_t)hb * SEQ + l0 + tid) * 16 + tblk] =
                rsum[0][tid] + rsum[1][tid] + rsum[2][tid] + rsum[3][tid];
        // next iteration's staging-sync guarantees these reads complete
        // before any wave rewrites rsum.
    }
}

// ---------------------------------------------------------------------------
// PV with fused normalization: p = e * invS (invS from psum partials) written
// BACK to fused (output), and p (bf16) @ V via MFMA -> attn_out fp32.
// No exp, no row max. XCD-chunked swizzle for vT L2 reuse.
// ---------------------------------------------------------------------------
__global__ __launch_bounds__(256) void pv_norm(
    float* __restrict__ fused, const unsigned short* __restrict__ vT,
    const float* __restrict__ psum, float* __restrict__ attn_out)
{
    const int orig = blockIdx.y * 16 + blockIdx.x;      // 0..767
    const int swz  = (orig & 7) * 96 + (orig >> 3);     // 768 = 8*96 -> 6 hb per XCD chunk
    const int l0 = (swz & 15) * 64;
    const int hb = swz >> 4;
    const int h = hb >> 2, b = hb & 3;

    __shared__ alignas(16) unsigned short sp[64 * 72];
    __shared__ alignas(16) unsigned short sv[64 * 72];
    __shared__ float sst[64];

    const int tid = threadIdx.x;
    if (tid < 64) {
        const float* pp = psum + ((size_t)hb * SEQ + l0 + tid) * 16;
        float s = 0.f;
        #pragma unroll
        for (int j = 0; j < 16; ++j) s += pp[j];
        sst[tid] = 1.0f / s;
    }
    const int wave = tid >> 6, lane = tid & 63;
    const int quad = lane >> 4, lq = lane & 15;

    f4_t acc[4];
    #pragma unroll
    for (int c = 0; c < 4; ++c)
        #pragma unroll
        for (int r = 0; r < 4; ++r) acc[c][r] = 0.f;
    __syncthreads();

    for (int tt = 0; tt < 16; ++tt) {
        #pragma unroll
        for (int i = 0; i < 4; ++i) {
            int c = tid + 256 * i;             // 1024 float4 chunks
            int row = c >> 4, f4i = c & 15;
            float* gp = fused + ((size_t)hb * SEQ + l0 + row) * SEQ + tt * 64 + f4i * 4;
            float4 v = *(const float4*)gp;
            float invS = sst[row];
            float4 pv;
            pv.x = v.x * invS;
            pv.y = v.y * invS;
            pv.z = v.z * invS;
            pv.w = v.w * invS;
            *(float4*)gp = pv;
            ushort4 pb;
            pb.x = f2b(pv.x); pb.y = f2b(pv.y); pb.z = f2b(pv.z); pb.w = f2b(pv.w);
            *(ushort4*)(sp + row * 72 + f4i * 4) = pb;
        }
        #pragma unroll
        for (int i = 0; i < 2; ++i) {
            int c = tid + 256 * i;
            int row = c >> 3, off = (c & 7) * 8;
            *(bf8_t*)(sv + row * 72 + off) =
                *(const bf8_t*)(vT + ((size_t)hb * 64 + row) * SEQ + tt * 64 + off);
        }
        __syncthreads();
        bf8_t af0 = *(const bf8_t*)(sp + (wave * 16 + lq) * 72 + quad * 8);
        bf8_t af1 = *(const bf8_t*)(sp + (wave * 16 + lq) * 72 + 32 + quad * 8);
        #pragma unroll
        for (int c = 0; c < 4; ++c) {
            bf8_t b0 = *(const bf8_t*)(sv + (c * 16 + lq) * 72 + quad * 8);
            bf8_t b1 = *(const bf8_t*)(sv + (c * 16 + lq) * 72 + 32 + quad * 8);
            acc[c] = __builtin_amdgcn_mfma_f32_16x16x32_bf16(af0, b0, acc[c], 0, 0, 0);
            acc[c] = __builtin_amdgcn_mfma_f32_16x16x32_bf16(af1, b1, acc[c], 0, 0, 0);
        }
        __syncthreads();
    }
    #pragma unroll
    for (int c = 0; c < 4; ++c)
        #pragma unroll
        for (int r = 0; r < 4; ++r) {
            int l = l0 + wave * 16 + quad * 4 + r;
            attn_out[((size_t)b * SEQ + l) * D_MODEL + h * 64 + c * 16 + lq] = acc[c][r];
        }
}

// ---------------------------------------------------------------------------
// FC: Out = X(fp32,cvt inline) * W^T + bias + residual -> fp32
// XCD-chunked swizzle like proj.
// ---------------------------------------------------------------------------
__global__ __launch_bounds__(256) void fc_mfma(
    const float* __restrict__ X, const unsigned short* __restrict__ W,
    const float* __restrict__ bias, const float* __restrict__ residual,
    float* __restrict__ Out)
{
    const int orig = blockIdx.y * 6 + blockIdx.x;       // 0..191
    const int swz  = (orig & 7) * 24 + (orig >> 3);
    const int m0 = (swz / 6) * 128;
    const int n0 = (swz % 6) * 128;

    __shared__ alignas(16) unsigned short As[128 * 72];
    __shared__ alignas(16) unsigned short Bs[128 * 72];

    const int tid = threadIdx.x;
    const int wave = tid >> 6, lane = tid & 63;
    const int quad = lane >> 4, lq = lane & 15;
    const int wr = wave >> 1, wc = wave & 1;

    f4_t acc[4][4];
    #pragma unroll
    for (int i = 0; i < 4; ++i)
        #pragma unroll
        for (int j = 0; j < 4; ++j)
            #pragma unroll
            for (int r = 0; r < 4; ++r) acc[i][j][r] = 0.0f;

    for (int k0 = 0; k0 < D_MODEL; k0 += 64) {
        #pragma unroll
        for (int i = 0; i < 4; ++i) {
            int c = tid + 256 * i;
            int row = c >> 3, off = (c & 7) * 8;
            const float* src = X + (size_t)(m0 + row) * D_MODEL + k0 + off;
            float4 u0 = *(const float4*)src;
            float4 u1 = *(const float4*)(src + 4);
            union { unsigned short u[8]; bf8_t v; } t;
            t.u[0] = f2b(u0.x); t.u[1] = f2b(u0.y); t.u[2] = f2b(u0.z); t.u[3] = f2b(u0.w);
            t.u[4] = f2b(u1.x); t.u[5] = f2b(u1.y); t.u[6] = f2b(u1.z); t.u[7] = f2b(u1.w);
            *(bf8_t*)(As + row * 72 + off) = t.v;
            *(bf8_t*)(Bs + row * 72 + off) =
                *(const bf8_t*)(W + (size_t)(n0 + row) * D_MODEL + k0 + off);
        }
        __syncthreads();
        #pragma unroll
        for (int ks = 0; ks < 2; ++ks) {
            bf8_t af[4], bfr[4];
            #pragma unroll
            for (int i = 0; i < 4; ++i)
                af[i] = *(const bf8_t*)(As + (wr * 64 + i * 16 + lq) * 72 + ks * 32 + quad * 8);
            #pragma unroll
            for (int j = 0; j < 4; ++j)
                bfr[j] = *(const bf8_t*)(Bs + (wc * 64 + j * 16 + lq) * 72 + ks * 32 + quad * 8);
            #pragma unroll
            for (int i = 0; i < 4; ++i)
                #pragma unroll
                for (int j = 0; j < 4; ++j)
                    acc[i][j] = __builtin_amdgcn_mfma_f32_16x16x32_bf16(af[i], bfr[j], acc[i][j], 0, 0, 0);
        }
        __syncthreads();
    }

    #pragma unroll
    for (int j = 0; j < 4; ++j) {
        int col = n0 + wc * 64 + j * 16 + lq;
        float bv_ = bias[col];
        #pragma unroll
        for (int i = 0; i < 4; ++i) {
            #pragma unroll
            for (int r = 0; r < 4; ++r) {
                int m = m0 + wr * 64 + i * 16 + quad * 4 + r;
                Out[(size_t)m * D_MODEL + col] =
                    acc[i][j][r] + bv_ + residual[(size_t)m * D_MODEL + col];
            }
        }
    }
}

// ---------------------------------------------------------------------------
// Kernel: LayerNorm over 768 per row -> d_out
// ---------------------------------------------------------------------------
__global__ __launch_bounds__(256) void ln_k(
    const float* __restrict__ X, const float* __restrict__ g,
    const float* __restrict__ bta, float* __restrict__ out)
{
    const int row = blockIdx.x;
    const float* x = X + (size_t)row * D_MODEL;
    const int tid = threadIdx.x;
    const int lane = tid & 63, wid = tid >> 6;
    __shared__ float s1[4], s2[4];

    float v0 = x[tid], v1 = x[tid + 256], v2 = x[tid + 512];
    float s = v0 + v1 + v2;
    float q = v0 * v0 + v1 * v1 + v2 * v2;
    #pragma unroll
    for (int o = 32; o > 0; o >>= 1) {
        s += __shfl_down(s, o, 64);
        q += __shfl_down(q, o, 64);
    }
    if (lane == 0) { s1[wid] = s; s2[wid] = q; }
    __syncthreads();
    const float sum = s1[0] + s1[1] + s1[2] + s1[3];
    const float sq  = s2[0] + s2[1] + s2[2] + s2[3];
    const float mu = sum * (1.0f / D_MODEL);
    const float var = sq * (1.0f / D_MODEL) - mu * mu;
    const float r = rsqrtf(var + 1e-5f);

    float* o = out + (size_t)row * D_MODEL;
    o[tid]       = (v0 - mu) * r * g[tid]       + bta[tid];
    o[tid + 256] = (v1 - mu) * r * g[tid + 256] + bta[tid + 256];
    o[tid + 512] = (v2 - mu) * r * g[tid + 512] + bta[tid + 512];
}

// ---------------------------------------------------------------------------
extern "C" void kernel_launch(void* const* d_in, const int* in_sizes, int n_in,
                              void* d_out, int out_size, void* d_ws, size_t ws_size,
                              hipStream_t stream)
{
    const float* q    = (const float*)d_in[0];
    const float* k    = (const float*)d_in[1];
    const float* v    = (const float*)d_in[2];
    const float* pl   = (const float*)d_in[3];
    const int*   mask = (const int*)d_in[4];
    const float* wq   = (const float*)d_in[5];
    const float* bq   = (const float*)d_in[6];
    const float* wk   = (const float*)d_in[7];
    const float* bk   = (const float*)d_in[8];
    const float* wv   = (const float*)d_in[9];
    const float* bv   = (const float*)d_in[10];
    const float* wfc  = (const float*)d_in[11];
    const float* bfc  = (const float*)d_in[12];
    const float* wloc = (const float*)d_in[13];
    const float* bloc = (const float*)d_in[14];
    const float* lng  = (const float*)d_in[15];
    const float* lnb  = (const float*)d_in[16];

    char* W8 = (char*)d_ws;
    const size_t SLOT = (size_t)PROJ_ELEMS * 2;            // 6291456 B
    // slots 0-2 (old qb/kb/vb) now scratch-only (proj converts inline)
    unsigned short* qh   = (unsigned short*)(W8 + 3 * SLOT);
    unsigned short* kh   = (unsigned short*)(W8 + 4 * SLOT);
    unsigned short* vh   = (unsigned short*)(W8 + 5 * SLOT);   // dead after vtrans
    unsigned short* vT   = (unsigned short*)(W8 + 6 * SLOT);
    unsigned short* wqb  = (unsigned short*)(W8 + 7 * SLOT);
    unsigned short* wkb  = (unsigned short*)(W8 + 7 * SLOT + 1179648);
    unsigned short* wvb  = (unsigned short*)(W8 + 7 * SLOT + 2 * 1179648);
    unsigned short* wfcb = (unsigned short*)(W8 + 7 * SLOT + 3 * 1179648);
    // overlays (sources dead by the time these are written):
    float* psum     = (float*)(W8 + 5 * SLOT);   // over vh (dead after vtrans), 3 MB
    float* attn_out = (float*)(W8 + 0 * SLOT);   // slots 0-1 (scratch)
    float* fc_out   = (float*)(W8 + 2 * SLOT);   // slots 2-3 (scratch + dead qh)

    float* out   = (float*)d_out;                 // [b][l][768]
    float* fused = out + (size_t)PROJ_ELEMS;      // [h][b][l][t] fp32

    cvt_k<<<dim3(576, 1, 4), 256, 0, stream>>>(wq, wk, wv, wfc, wqb, wkb, wvb, wfcb,
                                               D_MODEL * D_MODEL);
    proj_mfma<<<dim3(6, 32, 3), 256, 0, stream>>>(q, k, v, wqb, wkb, wvb,
                                                  bq, bk, bv, qh, kh, vh);
    vtrans<<<dim3(16, HB), 256, 0, stream>>>(vh, vT);
    attn_e<<<dim3(16, 64, BATCH), 256, 0, stream>>>(qh, kh, pl, mask, wloc, bloc,
                                                    fused, psum);
    pv_norm<<<dim3(16, HB), 256, 0, stream>>>(fused, vT, psum, attn_out);
    fc_mfma<<<dim3(6, 32), 256, 0, stream>>>(attn_out, wfcb, bfc, q, fc_out);
    ln_k<<<dim3(BATCH * SEQ), 256, 0, stream>>>(fc_out, lng, lnb, out);
}

// Round 3
// 571.005 us; speedup vs baseline: 1.0111x; 1.0082x over previous
//
#include <hip/hip_runtime.h>
#include <hip/hip_bf16.h>
#include <stdint.h>

#define D_MODEL 768
#define N_HEAD 12
#define D_HEAD 64
#define BATCH 4
#define SEQ 1024
#define HB 48
#define PROJ_ELEMS (BATCH * SEQ * D_MODEL)   // 3145728

typedef __attribute__((ext_vector_type(8))) short bf8_t;   // 8 bf16 = one MFMA A/B frag
typedef __attribute__((ext_vector_type(4))) float f4_t;    // 4 fp32 = one MFMA C/D frag

__device__ inline unsigned short f2b(float f) {           // RNE float->bf16
    union { float f; unsigned u; } v; v.f = f;
    unsigned r = v.u + 0x7FFFu + ((v.u >> 16) & 1u);
    return (unsigned short)(r >> 16);
}

// async 16B global->LDS DMA (m97 pattern). lds base must be wave-uniform;
// HW adds lane*16. size must be a literal.
#define GLOAD16(gp, lp)                                                      \
    __builtin_amdgcn_global_load_lds(                                        \
        (const __attribute__((address_space(1))) void*)(gp),                 \
        (__attribute__((address_space(3))) void*)(lp), 16, 0, 0)

// ---------------------------------------------------------------------------
// fp32 -> bf16 bulk convert (z picks one of up to 4 tensors)
// ---------------------------------------------------------------------------
__global__ __launch_bounds__(256) void cvt_k(
    const float* __restrict__ s0, const float* __restrict__ s1,
    const float* __restrict__ s2, const float* __restrict__ s3,
    unsigned short* __restrict__ d0, unsigned short* __restrict__ d1,
    unsigned short* __restrict__ d2, unsigned short* __restrict__ d3, int n)
{
    const int z = blockIdx.z;
    const float* s = (z == 0) ? s0 : (z == 1) ? s1 : (z == 2) ? s2 : s3;
    unsigned short* d = (z == 0) ? d0 : (z == 1) ? d1 : (z == 2) ? d2 : d3;
    int i = (blockIdx.x * 256 + threadIdx.x) * 4;
    if (i >= n) return;
    float4 v = *(const float4*)(s + i);
    ushort4 o;
    o.x = f2b(v.x); o.y = f2b(v.y); o.z = f2b(v.z); o.w = f2b(v.w);
    *(ushort4*)(d + i) = o;
}

// ---------------------------------------------------------------------------
// QKV projection: Y = X * W^T + bias, bf16 MFMA, 128x128 tile, BK=64.
// m97 structure: linear LDS + global_load_lds dwordx4 staging (A and B).
// Output head-split bf16: out[((h*4+b)*1024 + l)*64 + dh]
// ---------------------------------------------------------------------------
__global__ __launch_bounds__(256) void proj_mfma(
    const unsigned short* __restrict__ qb, const unsigned short* __restrict__ kb,
    const unsigned short* __restrict__ vb,
    const unsigned short* __restrict__ wqb, const unsigned short* __restrict__ wkb,
    const unsigned short* __restrict__ wvb,
    const float* __restrict__ bq, const float* __restrict__ bk, const float* __restrict__ bv,
    unsigned short* __restrict__ qh, unsigned short* __restrict__ kh,
    unsigned short* __restrict__ vh)
{
    const int z = blockIdx.z;
    const unsigned short* X = (z == 0) ? qb : (z == 1) ? kb : vb;
    const unsigned short* W = (z == 0) ? wqb : (z == 1) ? wkb : wvb;
    const float* bias = (z == 0) ? bq : (z == 1) ? bk : bv;
    unsigned short* Out = (z == 0) ? qh : (z == 1) ? kh : vh;

    const int m0 = blockIdx.y * 128;
    const int n0 = blockIdx.x * 128;

    __shared__ alignas(16) unsigned short As[128 * 64];   // linear, DMA-staged
    __shared__ alignas(16) unsigned short Bs[128 * 64];

    const int tid = threadIdx.x;
    const int wave = tid >> 6, lane = tid & 63;
    const int quad = lane >> 4, lq = lane & 15;
    const int wr = wave >> 1, wc = wave & 1;   // wave's 64x64 quadrant

    f4_t acc[4][4];
    #pragma unroll
    for (int i = 0; i < 4; ++i)
        #pragma unroll
        for (int j = 0; j < 4; ++j)
            #pragma unroll
            for (int r = 0; r < 4; ++r) acc[i][j][r] = 0.0f;

    for (int k0 = 0; k0 < D_MODEL; k0 += 64) {
        #pragma unroll
        for (int i = 0; i < 4; ++i) {
            int c = tid + 256 * i;            // 1024 16B-chunks per tile
            int row = c >> 3, off = (c & 7) * 8;
            int lbase = ((tid & ~63) + 256 * i) * 8;     // wave-uniform, shorts
            GLOAD16(X + (size_t)(m0 + row) * D_MODEL + k0 + off, As + lbase);
            GLOAD16(W + (size_t)(n0 + row) * D_MODEL + k0 + off, Bs + lbase);
        }
        __syncthreads();
        #pragma unroll
        for (int ks = 0; ks < 2; ++ks) {
            bf8_t af[4], bfr[4];
            #pragma unroll
            for (int i = 0; i < 4; ++i)
                af[i] = *(const bf8_t*)(As + (wr * 64 + i * 16 + lq) * 64 + ks * 32 + quad * 8);
            #pragma unroll
            for (int j = 0; j < 4; ++j)
                bfr[j] = *(const bf8_t*)(Bs + (wc * 64 + j * 16 + lq) * 64 + ks * 32 + quad * 8);
            #pragma unroll
            for (int i = 0; i < 4; ++i)
                #pragma unroll
                for (int j = 0; j < 4; ++j)
                    acc[i][j] = __builtin_amdgcn_mfma_f32_16x16x32_bf16(af[i], bfr[j], acc[i][j], 0, 0, 0);
        }
        __syncthreads();
    }

    const int bb = m0 >> 10;
    #pragma unroll
    for (int j = 0; j < 4; ++j) {
        int col = n0 + wc * 64 + j * 16 + lq;
        float bv_ = bias[col];
        int h = col >> 6, dh = col & 63;
        #pragma unroll
        for (int i = 0; i < 4; ++i) {
            #pragma unroll
            for (int r = 0; r < 4; ++r) {
                int m = m0 + wr * 64 + i * 16 + quad * 4 + r;
                int l = m & 1023;
                Out[(((size_t)(h * BATCH + bb) * SEQ + l) << 6) + dh] = f2b(acc[i][j][r] + bv_);
            }
        }
    }
}

// ---------------------------------------------------------------------------
// Transpose V per (hb, t-tile): vT[hb][dh][t] from vh[hb][t][dh]
// ---------------------------------------------------------------------------
__global__ __launch_bounds__(256) void vtrans(
    const unsigned short* __restrict__ vh, unsigned short* __restrict__ vT)
{
    const int hb = blockIdx.y, tt = blockIdx.x;
    __shared__ alignas(16) unsigned short s[64 * 72];
    const int tid = threadIdx.x;
    #pragma unroll
    for (int i = 0; i < 2; ++i) {
        int c = tid + 256 * i;
        int t = c >> 3, off = (c & 7) * 8;
        *(bf8_t*)(s + t * 72 + off) =
            *(const bf8_t*)(vh + ((size_t)hb * SEQ + tt * 64 + t) * 64 + off);
    }
    __syncthreads();
    #pragma unroll
    for (int i = 0; i < 2; ++i) {
        int c = tid + 256 * i;
        int dh = c >> 3, toff = (c & 7) * 8;
        union { unsigned short u[8]; bf8_t v; } tmp;
        #pragma unroll
        for (int j = 0; j < 8; ++j) tmp.u[j] = s[(toff + j) * 72 + dh];
        *(bf8_t*)(vT + ((size_t)hb * 64 + dh) * SEQ + tt * 64 + toff) = tmp.v;
    }
}

// ---------------------------------------------------------------------------
// Fused loc + QK^T + mask -> UNNORMALIZED scores e = clip(loc)*exp(qk/8)
// written to fused[h][b][l][t] (fp32), plus deterministic per-row partial
// sums psum[(hb*SEQ+l)*16 + tblk]. No row max needed: |qk/8| <~ 2 so the
// un-shifted exp is safely in fp32 range.
// ---------------------------------------------------------------------------
__global__ __launch_bounds__(256) void attn_e(
    const unsigned short* __restrict__ qh, const unsigned short* __restrict__ kh,
    const float* __restrict__ pl, const int* __restrict__ mask,
    const float* __restrict__ wloc, const float* __restrict__ bloc,
    float* __restrict__ fused, float* __restrict__ psum)
{
    const int orig = (blockIdx.z * 64 + blockIdx.y) * 16 + blockIdx.x;  // 0..4095
    const int swz  = (orig & 7) * 512 + (orig >> 3);                    // 4096 = 8*512
    const int tblk = swz & 15;
    const int t0 = tblk * 64;
    const int l0 = ((swz >> 4) & 63) * 16;
    const int b  = swz >> 10;

    __shared__ alignas(16) float spl[16 * 324];            // [l][t*5], padded stride
    __shared__ alignas(16) unsigned short sq[16 * 72];
    __shared__ alignas(16) unsigned short sk[64 * 72];
    __shared__ float rsum[4][16];                          // [wave][row]

    const int tid = threadIdx.x;
    {   // cooperative pl tile load: 16 rows x 320 floats = 1280 float4, 5/thread
        int r = tid >> 4, c16 = tid & 15;
        const float* src = pl + (((size_t)(b * SEQ + l0 + r) * SEQ) + t0) * 5;
        float* dst = spl + r * 324;
        #pragma unroll
        for (int j = 0; j < 5; ++j) {
            int f4i = j * 16 + c16;            // 0..79
            *(float4*)(dst + f4i * 4) = *(const float4*)(src + f4i * 4);
        }
    }
    const int wave = tid >> 6, lane = tid & 63;
    const int quad = lane >> 4, lq = lane & 15;
    const int mk = mask[b * SEQ + t0 + wave * 16 + lq];

    for (int h = 0; h < N_HEAD; ++h) {
        const int hb = h * BATCH + b;
        if (tid < 128) {   // stage Q: 16 rows x 8 chunks
            int row = tid >> 3, off = (tid & 7) * 8;
            *(bf8_t*)(sq + row * 72 + off) =
                *(const bf8_t*)(qh + (((size_t)hb * SEQ) + l0 + row) * 64 + off);
        }
        #pragma unroll
        for (int i = 0; i < 2; ++i) {          // stage K: 64 rows x 8 chunks
            int c = tid + 256 * i;
            int r2 = c >> 3, o2 = (c & 7) * 8;
            *(bf8_t*)(sk + r2 * 72 + o2) =
                *(const bf8_t*)(kh + (((size_t)hb * SEQ) + t0 + r2) * 64 + o2);
        }
        __syncthreads();

        const float wl0 = wloc[h * 5 + 0], wl1 = wloc[h * 5 + 1], wl2 = wloc[h * 5 + 2];
        const float wl3 = wloc[h * 5 + 3], wl4 = wloc[h * 5 + 4];
        const float bl = bloc[h];

        bf8_t a0 = *(const bf8_t*)(sq + lq * 72 + quad * 8);
        bf8_t a1 = *(const bf8_t*)(sq + lq * 72 + 32 + quad * 8);
        bf8_t b0 = *(const bf8_t*)(sk + (wave * 16 + lq) * 72 + quad * 8);
        bf8_t b1 = *(const bf8_t*)(sk + (wave * 16 + lq) * 72 + 32 + quad * 8);
        f4_t acc = {0.f, 0.f, 0.f, 0.f};
        acc = __builtin_amdgcn_mfma_f32_16x16x32_bf16(a0, b0, acc, 0, 0, 0);
        acc = __builtin_amdgcn_mfma_f32_16x16x32_bf16(a1, b1, acc, 0, 0, 0);

        const int tt = wave * 16 + lq;          // tile-local t (0..63)
        float sr[4];
        #pragma unroll
        for (int r = 0; r < 4; ++r) {
            int ll = quad * 4 + r;              // tile-local l (0..15)
            const float* p5 = spl + ll * 324 + tt * 5;
            float loc = fmaf(wl0, p5[0], fmaf(wl1, p5[1], fmaf(wl2, p5[2],
                        fmaf(wl3, p5[3], fmaf(wl4, p5[4], bl)))));
            float e = mk ? 0.0f : fmaxf(loc, 1e-6f) * __expf(0.125f * acc[r]);
            fused[((size_t)hb * SEQ + l0 + ll) * SEQ + t0 + tt] = e;
            sr[r] = e;
        }
        // sum over the wave's 16 t (lq bits 0..3), per row
        #pragma unroll
        for (int o = 1; o < 16; o <<= 1) {
            sr[0] += __shfl_xor(sr[0], o, 64);
            sr[1] += __shfl_xor(sr[1], o, 64);
            sr[2] += __shfl_xor(sr[2], o, 64);
            sr[3] += __shfl_xor(sr[3], o, 64);
        }
        if (lq == 0) {
            #pragma unroll
            for (int r = 0; r < 4; ++r) rsum[wave][quad * 4 + r] = sr[r];
        }
        __syncthreads();                        // rsum visible; sq/sk reusable
        if (tid < 16)                           // combine 4 waves, write partial sum
            psum[((size_t)hb * SEQ + l0 + tid) * 16 + tblk] =
                rsum[0][tid] + rsum[1][tid] + rsum[2][tid] + rsum[3][tid];
    }
}

// ---------------------------------------------------------------------------
// PV with fused normalization: p = e * invS written BACK to fused (output),
// and p (bf16) @ V via MFMA -> attn_out BF16 (feeds fc's DMA staging; same
// f2b rounding point as before, so MFMA inputs are bit-identical).
// ---------------------------------------------------------------------------
__global__ __launch_bounds__(256) void pv_norm(
    float* __restrict__ fused, const unsigned short* __restrict__ vT,
    const float* __restrict__ psum, unsigned short* __restrict__ attn_out)
{
    const int orig = blockIdx.y * 16 + blockIdx.x;      // 0..767
    const int swz  = (orig & 7) * 96 + (orig >> 3);     // 768 = 8*96
    const int l0 = (swz & 15) * 64;
    const int hb = swz >> 4;
    const int h = hb >> 2, b = hb & 3;

    __shared__ alignas(16) unsigned short sp[64 * 72];
    __shared__ alignas(16) unsigned short sv[64 * 72];
    __shared__ float sst[64];

    const int tid = threadIdx.x;
    if (tid < 64) {
        const float* pp = psum + ((size_t)hb * SEQ + l0 + tid) * 16;
        float s = 0.f;
        #pragma unroll
        for (int j = 0; j < 16; ++j) s += pp[j];
        sst[tid] = 1.0f / s;
    }
    const int wave = tid >> 6, lane = tid & 63;
    const int quad = lane >> 4, lq = lane & 15;

    f4_t acc[4];
    #pragma unroll
    for (int c = 0; c < 4; ++c)
        #pragma unroll
        for (int r = 0; r < 4; ++r) acc[c][r] = 0.f;
    __syncthreads();

    for (int tt = 0; tt < 16; ++tt) {
        #pragma unroll
        for (int i = 0; i < 4; ++i) {
            int c = tid + 256 * i;             // 1024 float4 chunks
            int row = c >> 4, f4i = c & 15;
            float* gp = fused + ((size_t)hb * SEQ + l0 + row) * SEQ + tt * 64 + f4i * 4;
            float4 v = *(const float4*)gp;
            float invS = sst[row];
            float4 pv;
            pv.x = v.x * invS;
            pv.y = v.y * invS;
            pv.z = v.z * invS;
            pv.w = v.w * invS;
            *(float4*)gp = pv;
            ushort4 pb;
            pb.x = f2b(pv.x); pb.y = f2b(pv.y); pb.z = f2b(pv.z); pb.w = f2b(pv.w);
            *(ushort4*)(sp + row * 72 + f4i * 4) = pb;
        }
        #pragma unroll
        for (int i = 0; i < 2; ++i) {
            int c = tid + 256 * i;
            int row = c >> 3, off = (c & 7) * 8;
            *(bf8_t*)(sv + row * 72 + off) =
                *(const bf8_t*)(vT + ((size_t)hb * 64 + row) * SEQ + tt * 64 + off);
        }
        __syncthreads();
        bf8_t af0 = *(const bf8_t*)(sp + (wave * 16 + lq) * 72 + quad * 8);
        bf8_t af1 = *(const bf8_t*)(sp + (wave * 16 + lq) * 72 + 32 + quad * 8);
        #pragma unroll
        for (int c = 0; c < 4; ++c) {
            bf8_t b0 = *(const bf8_t*)(sv + (c * 16 + lq) * 72 + quad * 8);
            bf8_t b1 = *(const bf8_t*)(sv + (c * 16 + lq) * 72 + 32 + quad * 8);
            acc[c] = __builtin_amdgcn_mfma_f32_16x16x32_bf16(af0, b0, acc[c], 0, 0, 0);
            acc[c] = __builtin_amdgcn_mfma_f32_16x16x32_bf16(af1, b1, acc[c], 0, 0, 0);
        }
        __syncthreads();
    }
    #pragma unroll
    for (int c = 0; c < 4; ++c)
        #pragma unroll
        for (int r = 0; r < 4; ++r) {
            int l = l0 + wave * 16 + quad * 4 + r;
            attn_out[((size_t)b * SEQ + l) * D_MODEL + h * 64 + c * 16 + lq] = f2b(acc[c][r]);
        }
}

// ---------------------------------------------------------------------------
// FC: Out = X(bf16) * W^T + bias + residual -> fp32. m97 structure:
// linear LDS + global_load_lds staging for A and B.
// ---------------------------------------------------------------------------
__global__ __launch_bounds__(256) void fc_mfma(
    const unsigned short* __restrict__ X, const unsigned short* __restrict__ W,
    const float* __restrict__ bias, const float* __restrict__ residual,
    float* __restrict__ Out)
{
    const int m0 = blockIdx.y * 128;
    const int n0 = blockIdx.x * 128;

    __shared__ alignas(16) unsigned short As[128 * 64];
    __shared__ alignas(16) unsigned short Bs[128 * 64];

    const int tid = threadIdx.x;
    const int wave = tid >> 6, lane = tid & 63;
    const int quad = lane >> 4, lq = lane & 15;
    const int wr = wave >> 1, wc = wave & 1;

    f4_t acc[4][4];
    #pragma unroll
    for (int i = 0; i < 4; ++i)
        #pragma unroll
        for (int j = 0; j < 4; ++j)
            #pragma unroll
            for (int r = 0; r < 4; ++r) acc[i][j][r] = 0.0f;

    for (int k0 = 0; k0 < D_MODEL; k0 += 64) {
        #pragma unroll
        for (int i = 0; i < 4; ++i) {
            int c = tid + 256 * i;
            int row = c >> 3, off = (c & 7) * 8;
            int lbase = ((tid & ~63) + 256 * i) * 8;     // wave-uniform, shorts
            GLOAD16(X + (size_t)(m0 + row) * D_MODEL + k0 + off, As + lbase);
            GLOAD16(W + (size_t)(n0 + row) * D_MODEL + k0 + off, Bs + lbase);
        }
        __syncthreads();
        #pragma unroll
        for (int ks = 0; ks < 2; ++ks) {
            bf8_t af[4], bfr[4];
            #pragma unroll
            for (int i = 0; i < 4; ++i)
                af[i] = *(const bf8_t*)(As + (wr * 64 + i * 16 + lq) * 64 + ks * 32 + quad * 8);
            #pragma unroll
            for (int j = 0; j < 4; ++j)
                bfr[j] = *(const bf8_t*)(Bs + (wc * 64 + j * 16 + lq) * 64 + ks * 32 + quad * 8);
            #pragma unroll
            for (int i = 0; i < 4; ++i)
                #pragma unroll
                for (int j = 0; j < 4; ++j)
                    acc[i][j] = __builtin_amdgcn_mfma_f32_16x16x32_bf16(af[i], bfr[j], acc[i][j], 0, 0, 0);
        }
        __syncthreads();
    }

    #pragma unroll
    for (int j = 0; j < 4; ++j) {
        int col = n0 + wc * 64 + j * 16 + lq;
        float bv_ = bias[col];
        #pragma unroll
        for (int i = 0; i < 4; ++i) {
            #pragma unroll
            for (int r = 0; r < 4; ++r) {
                int m = m0 + wr * 64 + i * 16 + quad * 4 + r;
                Out[(size_t)m * D_MODEL + col] =
                    acc[i][j][r] + bv_ + residual[(size_t)m * D_MODEL + col];
            }
        }
    }
}

// ---------------------------------------------------------------------------
// Kernel: LayerNorm over 768 per row -> d_out
// ---------------------------------------------------------------------------
__global__ __launch_bounds__(256) void ln_k(
    const float* __restrict__ X, const float* __restrict__ g,
    const float* __restrict__ bta, float* __restrict__ out)
{
    const int row = blockIdx.x;
    const float* x = X + (size_t)row * D_MODEL;
    const int tid = threadIdx.x;
    const int lane = tid & 63, wid = tid >> 6;
    __shared__ float s1[4], s2[4];

    float v0 = x[tid], v1 = x[tid + 256], v2 = x[tid + 512];
    float s = v0 + v1 + v2;
    float q = v0 * v0 + v1 * v1 + v2 * v2;
    #pragma unroll
    for (int o = 32; o > 0; o >>= 1) {
        s += __shfl_down(s, o, 64);
        q += __shfl_down(q, o, 64);
    }
    if (lane == 0) { s1[wid] = s; s2[wid] = q; }
    __syncthreads();
    const float sum = s1[0] + s1[1] + s1[2] + s1[3];
    const float sq  = s2[0] + s2[1] + s2[2] + s2[3];
    const float mu = sum * (1.0f / D_MODEL);
    const float var = sq * (1.0f / D_MODEL) - mu * mu;
    const float r = rsqrtf(var + 1e-5f);

    float* o = out + (size_t)row * D_MODEL;
    o[tid]       = (v0 - mu) * r * g[tid]       + bta[tid];
    o[tid + 256] = (v1 - mu) * r * g[tid + 256] + bta[tid + 256];
    o[tid + 512] = (v2 - mu) * r * g[tid + 512] + bta[tid + 512];
}

// ---------------------------------------------------------------------------
extern "C" void kernel_launch(void* const* d_in, const int* in_sizes, int n_in,
                              void* d_out, int out_size, void* d_ws, size_t ws_size,
                              hipStream_t stream)
{
    const float* q    = (const float*)d_in[0];
    const float* k    = (const float*)d_in[1];
    const float* v    = (const float*)d_in[2];
    const float* pl   = (const float*)d_in[3];
    const int*   mask = (const int*)d_in[4];
    const float* wq   = (const float*)d_in[5];
    const float* bq   = (const float*)d_in[6];
    const float* wk   = (const float*)d_in[7];
    const float* bk   = (const float*)d_in[8];
    const float* wv   = (const float*)d_in[9];
    const float* bv   = (const float*)d_in[10];
    const float* wfc  = (const float*)d_in[11];
    const float* bfc  = (const float*)d_in[12];
    const float* wloc = (const float*)d_in[13];
    const float* bloc = (const float*)d_in[14];
    const float* lng  = (const float*)d_in[15];
    const float* lnb  = (const float*)d_in[16];

    char* W8 = (char*)d_ws;
    const size_t SLOT = (size_t)PROJ_ELEMS * 2;            // 6291456 B per bf16 tensor
    unsigned short* qb   = (unsigned short*)(W8 + 0 * SLOT);
    unsigned short* kb   = (unsigned short*)(W8 + 1 * SLOT);
    unsigned short* vb   = (unsigned short*)(W8 + 2 * SLOT);
    unsigned short* qh   = (unsigned short*)(W8 + 3 * SLOT);
    unsigned short* kh   = (unsigned short*)(W8 + 4 * SLOT);
    unsigned short* vh   = (unsigned short*)(W8 + 5 * SLOT);   // dead after vtrans
    unsigned short* vT   = (unsigned short*)(W8 + 6 * SLOT);
    unsigned short* wqb  = (unsigned short*)(W8 + 7 * SLOT);
    unsigned short* wkb  = (unsigned short*)(W8 + 7 * SLOT + 1179648);
    unsigned short* wvb  = (unsigned short*)(W8 + 7 * SLOT + 2 * 1179648);
    unsigned short* wfcb = (unsigned short*)(W8 + 7 * SLOT + 3 * 1179648);
    // overlays (sources dead by the time these are written):
    float*          psum     = (float*)(W8 + 5 * SLOT);          // over vh (dead after vtrans)
    unsigned short* attn_out = (unsigned short*)(W8 + 0 * SLOT); // over qb (dead after proj)
    float*          fc_out   = (float*)(W8 + 2 * SLOT);          // over vb+qh (dead)

    float* out   = (float*)d_out;                 // [b][l][768]
    float* fused = out + (size_t)PROJ_ELEMS;      // [h][b][l][t] fp32

    cvt_k<<<dim3(3072, 1, 3), 256, 0, stream>>>(q, k, v, v, qb, kb, vb, vb, PROJ_ELEMS);
    cvt_k<<<dim3(576, 1, 4), 256, 0, stream>>>(wq, wk, wv, wfc, wqb, wkb, wvb, wfcb,
                                               D_MODEL * D_MODEL);
    proj_mfma<<<dim3(6, 32, 3), 256, 0, stream>>>(qb, kb, vb, wqb, wkb, wvb,
                                                  bq, bk, bv, qh, kh, vh);
    vtrans<<<dim3(16, HB), 256, 0, stream>>>(vh, vT);
    attn_e<<<dim3(16, 64, BATCH), 256, 0, stream>>>(qh, kh, pl, mask, wloc, bloc,
                                                    fused, psum);
    pv_norm<<<dim3(16, HB), 256, 0, stream>>>(fused, vT, psum, attn_out);
    fc_mfma<<<dim3(6, 32), 256, 0, stream>>>(attn_out, wfcb, bfc, q, fc_out);
    ln_k<<<dim3(BATCH * SEQ), 256, 0, stream>>>(fc_out, lng, lnb, out);
}

// Round 4
// 570.324 us; speedup vs baseline: 1.0123x; 1.0012x over previous
//
#include <hip/hip_runtime.h>
#include <hip/hip_bf16.h>
#include <stdint.h>

#define D_MODEL 768
#define N_HEAD 12
#define D_HEAD 64
#define BATCH 4
#define SEQ 1024
#define HB 48
#define PROJ_ELEMS (BATCH * SEQ * D_MODEL)   // 3145728

typedef __attribute__((ext_vector_type(8))) short bf8_t;   // 8 bf16 = one MFMA A/B frag
typedef __attribute__((ext_vector_type(4))) float f4_t;    // 4 fp32 = one MFMA C/D frag

__device__ inline unsigned short f2b(float f) {           // RNE float->bf16
    union { float f; unsigned u; } v; v.f = f;
    unsigned r = v.u + 0x7FFFu + ((v.u >> 16) & 1u);
    return (unsigned short)(r >> 16);
}

// async 16B global->LDS DMA (m97 pattern). lds base must be wave-uniform;
// HW adds lane*16. size must be a literal.
#define GLOAD16(gp, lp)                                                      \
    __builtin_amdgcn_global_load_lds(                                        \
        (const __attribute__((address_space(1))) void*)(gp),                 \
        (__attribute__((address_space(3))) void*)(lp), 16, 0, 0)

// ---------------------------------------------------------------------------
// fp32 -> bf16 bulk convert (z picks one of up to 4 tensors)
// ---------------------------------------------------------------------------
__global__ __launch_bounds__(256) void cvt_k(
    const float* __restrict__ s0, const float* __restrict__ s1,
    const float* __restrict__ s2, const float* __restrict__ s3,
    unsigned short* __restrict__ d0, unsigned short* __restrict__ d1,
    unsigned short* __restrict__ d2, unsigned short* __restrict__ d3, int n)
{
    const int z = blockIdx.z;
    const float* s = (z == 0) ? s0 : (z == 1) ? s1 : (z == 2) ? s2 : s3;
    unsigned short* d = (z == 0) ? d0 : (z == 1) ? d1 : (z == 2) ? d2 : d3;
    int i = (blockIdx.x * 256 + threadIdx.x) * 4;
    if (i >= n) return;
    float4 v = *(const float4*)(s + i);
    ushort4 o;
    o.x = f2b(v.x); o.y = f2b(v.y); o.z = f2b(v.z); o.w = f2b(v.w);
    *(ushort4*)(d + i) = o;
}

// ---------------------------------------------------------------------------
// QKV projection: Y = X * W^T + bias, bf16 MFMA, 128x128 tile, BK=64.
// m97 structure: linear LDS + global_load_lds dwordx4 staging (A and B).
// Output head-split bf16: out[((h*4+b)*1024 + l)*64 + dh]
// ---------------------------------------------------------------------------
__global__ __launch_bounds__(256) void proj_mfma(
    const unsigned short* __restrict__ qb, const unsigned short* __restrict__ kb,
    const unsigned short* __restrict__ vb,
    const unsigned short* __restrict__ wqb, const unsigned short* __restrict__ wkb,
    const unsigned short* __restrict__ wvb,
    const float* __restrict__ bq, const float* __restrict__ bk, const float* __restrict__ bv,
    unsigned short* __restrict__ qh, unsigned short* __restrict__ kh,
    unsigned short* __restrict__ vh)
{
    const int z = blockIdx.z;
    const unsigned short* X = (z == 0) ? qb : (z == 1) ? kb : vb;
    const unsigned short* W = (z == 0) ? wqb : (z == 1) ? wkb : wvb;
    const float* bias = (z == 0) ? bq : (z == 1) ? bk : bv;
    unsigned short* Out = (z == 0) ? qh : (z == 1) ? kh : vh;

    const int m0 = blockIdx.y * 128;
    const int n0 = blockIdx.x * 128;

    __shared__ alignas(16) unsigned short As[128 * 64];   // linear, DMA-staged
    __shared__ alignas(16) unsigned short Bs[128 * 64];

    const int tid = threadIdx.x;
    const int wave = tid >> 6, lane = tid & 63;
    const int quad = lane >> 4, lq = lane & 15;
    const int wr = wave >> 1, wc = wave & 1;   // wave's 64x64 quadrant

    f4_t acc[4][4];
    #pragma unroll
    for (int i = 0; i < 4; ++i)
        #pragma unroll
        for (int j = 0; j < 4; ++j)
            #pragma unroll
            for (int r = 0; r < 4; ++r) acc[i][j][r] = 0.0f;

    for (int k0 = 0; k0 < D_MODEL; k0 += 64) {
        #pragma unroll
        for (int i = 0; i < 4; ++i) {
            int c = tid + 256 * i;            // 1024 16B-chunks per tile
            int row = c >> 3, off = (c & 7) * 8;
            int lbase = ((tid & ~63) + 256 * i) * 8;     // wave-uniform, shorts
            GLOAD16(X + (size_t)(m0 + row) * D_MODEL + k0 + off, As + lbase);
            GLOAD16(W + (size_t)(n0 + row) * D_MODEL + k0 + off, Bs + lbase);
        }
        __syncthreads();
        #pragma unroll
        for (int ks = 0; ks < 2; ++ks) {
            bf8_t af[4], bfr[4];
            #pragma unroll
            for (int i = 0; i < 4; ++i)
                af[i] = *(const bf8_t*)(As + (wr * 64 + i * 16 + lq) * 64 + ks * 32 + quad * 8);
            #pragma unroll
            for (int j = 0; j < 4; ++j)
                bfr[j] = *(const bf8_t*)(Bs + (wc * 64 + j * 16 + lq) * 64 + ks * 32 + quad * 8);
            #pragma unroll
            for (int i = 0; i < 4; ++i)
                #pragma unroll
                for (int j = 0; j < 4; ++j)
                    acc[i][j] = __builtin_amdgcn_mfma_f32_16x16x32_bf16(af[i], bfr[j], acc[i][j], 0, 0, 0);
        }
        __syncthreads();
    }

    const int bb = m0 >> 10;
    #pragma unroll
    for (int j = 0; j < 4; ++j) {
        int col = n0 + wc * 64 + j * 16 + lq;
        float bv_ = bias[col];
        int h = col >> 6, dh = col & 63;
        #pragma unroll
        for (int i = 0; i < 4; ++i) {
            #pragma unroll
            for (int r = 0; r < 4; ++r) {
                int m = m0 + wr * 64 + i * 16 + quad * 4 + r;
                int l = m & 1023;
                Out[(((size_t)(h * BATCH + bb) * SEQ + l) << 6) + dh] = f2b(acc[i][j][r] + bv_);
            }
        }
    }
}

// ---------------------------------------------------------------------------
// Transpose V per (hb, t-tile): vT[hb][dh][t] from vh[hb][t][dh]
// ---------------------------------------------------------------------------
__global__ __launch_bounds__(256) void vtrans(
    const unsigned short* __restrict__ vh, unsigned short* __restrict__ vT)
{
    const int hb = blockIdx.y, tt = blockIdx.x;
    __shared__ alignas(16) unsigned short s[64 * 72];
    const int tid = threadIdx.x;
    #pragma unroll
    for (int i = 0; i < 2; ++i) {
        int c = tid + 256 * i;
        int t = c >> 3, off = (c & 7) * 8;
        *(bf8_t*)(s + t * 72 + off) =
            *(const bf8_t*)(vh + ((size_t)hb * SEQ + tt * 64 + t) * 64 + off);
    }
    __syncthreads();
    #pragma unroll
    for (int i = 0; i < 2; ++i) {
        int c = tid + 256 * i;
        int dh = c >> 3, toff = (c & 7) * 8;
        union { unsigned short u[8]; bf8_t v; } tmp;
        #pragma unroll
        for (int j = 0; j < 8; ++j) tmp.u[j] = s[(toff + j) * 72 + dh];
        *(bf8_t*)(vT + ((size_t)hb * 64 + dh) * SEQ + tt * 64 + toff) = tmp.v;
    }
}

// ---------------------------------------------------------------------------
// FUSED attention: per block = (head h, batch b, 16 l-rows).
// Pass 1: loop 16 t-tiles: QK MFMA + loc -> e (fp32) kept in LDS [16][1024],
//         row sums accumulated in registers (no global e traffic, no psum).
// Pass 2: loop 16 t-tiles: P = e*invS built in-register from LDS, written
//         ONCE to fused (final normalized fp32), PV MFMA -> attn_out bf16.
// Numerics identical to the previous passing split version (same rounding
// points; only fp32 sum order differs by ulps).
// LDS = 77.6 KB -> 2 blocks/CU. XCD swizzle groups the 12 heads sharing a
// (b,l0) pl-slice onto one XCD so pl reads are L2-hot.
// ---------------------------------------------------------------------------
__global__ __launch_bounds__(256) void attn_pv(
    const unsigned short* __restrict__ qh, const unsigned short* __restrict__ kh,
    const unsigned short* __restrict__ vT,
    const float* __restrict__ pl, const int* __restrict__ mask,
    const float* __restrict__ wloc, const float* __restrict__ bloc,
    float* __restrict__ fused, unsigned short* __restrict__ attn_out)
{
    const int orig = blockIdx.x;                       // 0..3071
    const int swz  = (orig & 7) * 384 + (orig >> 3);   // bijective (3072 = 8*384)
    const int h  = swz % 12;
    const int g  = swz / 12;                           // 0..255 = (b, l-tile)
    const int b  = g >> 6;
    const int l0 = (g & 63) * 16;
    const int hb = h * BATCH + b;

    __shared__ float eS[16 * 1028];                    // e rows, stride-pad 1028
    __shared__ alignas(16) unsigned short sq[16 * 72];
    __shared__ alignas(16) unsigned short skv[64 * 72]; // K (pass1) / V^T (pass2)
    __shared__ float rsum[4][16];
    __shared__ float sinv[16];

    const int tid = threadIdx.x;
    const int wave = tid >> 6, lane = tid & 63;
    const int quad = lane >> 4, lq = lane & 15;

    // stage Q once (16 rows x 8 chunks); first in-loop barrier orders it
    if (tid < 128) {
        int row = tid >> 3, off = (tid & 7) * 8;
        *(bf8_t*)(sq + row * 72 + off) =
            *(const bf8_t*)(qh + (((size_t)hb * SEQ) + l0 + row) * 64 + off);
    }

    const float wl0 = wloc[h * 5 + 0], wl1 = wloc[h * 5 + 1], wl2 = wloc[h * 5 + 2];
    const float wl3 = wloc[h * 5 + 3], wl4 = wloc[h * 5 + 4];
    const float bl = bloc[h];

    // ---------------- pass 1: e + row sums ----------------
    float sr[4] = {0.f, 0.f, 0.f, 0.f};
    for (int tt = 0; tt < 16; ++tt) {
        #pragma unroll
        for (int i = 0; i < 2; ++i) {          // stage K-tile: 64 rows x 8 chunks
            int c = tid + 256 * i;
            int r2 = c >> 3, o2 = (c & 7) * 8;
            *(bf8_t*)(skv + r2 * 72 + o2) =
                *(const bf8_t*)(kh + (((size_t)hb * SEQ) + tt * 64 + r2) * 64 + o2);
        }
        const int t = tt * 64 + wave * 16 + lq;
        const int mk = mask[b * SEQ + t];
        float p5[4][5];
        #pragma unroll
        for (int r = 0; r < 4; ++r) {
            const float* pp = pl + (((size_t)(b * SEQ + l0 + quad * 4 + r) * SEQ) + t) * 5;
            #pragma unroll
            for (int j = 0; j < 5; ++j) p5[r][j] = pp[j];
        }
        __syncthreads();

        bf8_t a0 = *(const bf8_t*)(sq + lq * 72 + quad * 8);
        bf8_t a1 = *(const bf8_t*)(sq + lq * 72 + 32 + quad * 8);
        bf8_t b0 = *(const bf8_t*)(skv + (wave * 16 + lq) * 72 + quad * 8);
        bf8_t b1 = *(const bf8_t*)(skv + (wave * 16 + lq) * 72 + 32 + quad * 8);
        f4_t qk = {0.f, 0.f, 0.f, 0.f};
        qk = __builtin_amdgcn_mfma_f32_16x16x32_bf16(a0, b0, qk, 0, 0, 0);
        qk = __builtin_amdgcn_mfma_f32_16x16x32_bf16(a1, b1, qk, 0, 0, 0);

        #pragma unroll
        for (int r = 0; r < 4; ++r) {
            int ll = quad * 4 + r;
            float loc = fmaf(wl0, p5[r][0], fmaf(wl1, p5[r][1], fmaf(wl2, p5[r][2],
                        fmaf(wl3, p5[r][3], fmaf(wl4, p5[r][4], bl)))));
            float e = mk ? 0.0f : fmaxf(loc, 1e-6f) * __expf(0.125f * qk[r]);
            eS[ll * 1028 + t] = e;
            sr[r] += e;
        }
        __syncthreads();
    }
    // wave's 16-t partial sums -> block row sums -> invS
    #pragma unroll
    for (int o = 1; o < 16; o <<= 1) {
        sr[0] += __shfl_xor(sr[0], o, 64);
        sr[1] += __shfl_xor(sr[1], o, 64);
        sr[2] += __shfl_xor(sr[2], o, 64);
        sr[3] += __shfl_xor(sr[3], o, 64);
    }
    if (lq == 0) {
        #pragma unroll
        for (int r = 0; r < 4; ++r) rsum[wave][quad * 4 + r] = sr[r];
    }
    __syncthreads();
    if (tid < 16)
        sinv[tid] = 1.0f / (rsum[0][tid] + rsum[1][tid] + rsum[2][tid] + rsum[3][tid]);
    __syncthreads();

    // ---------------- pass 2: fused write + PV ----------------
    const float inv = sinv[lq];
    f4_t acc = {0.f, 0.f, 0.f, 0.f};           // wave's 16l x 16dh tile
    for (int tt = 0; tt < 16; ++tt) {
        #pragma unroll
        for (int i = 0; i < 2; ++i) {          // stage V^T-tile: 64 dh x 8 chunks
            int c = tid + 256 * i;
            int row = c >> 3, off = (c & 7) * 8;
            *(bf8_t*)(skv + row * 72 + off) =
                *(const bf8_t*)(vT + ((size_t)hb * 64 + row) * SEQ + tt * 64 + off);
        }
        __syncthreads();
        #pragma unroll
        for (int ks = 0; ks < 2; ++ks) {
            const float* ep = eS + lq * 1028 + tt * 64 + ks * 32 + quad * 8;
            float4 ea = *(const float4*)ep;
            float4 eb = *(const float4*)(ep + 4);
            ea.x *= inv; ea.y *= inv; ea.z *= inv; ea.w *= inv;
            eb.x *= inv; eb.y *= inv; eb.z *= inv; eb.w *= inv;
            if ((tt & 3) == wave) {            // rotating duty wave writes fused
                float* fp = fused + ((size_t)hb * SEQ + l0 + lq) * SEQ
                                  + tt * 64 + ks * 32 + quad * 8;
                *(float4*)fp = ea;
                *(float4*)(fp + 4) = eb;
            }
            union { unsigned short u[8]; bf8_t v; } pa;
            pa.u[0] = f2b(ea.x); pa.u[1] = f2b(ea.y); pa.u[2] = f2b(ea.z); pa.u[3] = f2b(ea.w);
            pa.u[4] = f2b(eb.x); pa.u[5] = f2b(eb.y); pa.u[6] = f2b(eb.z); pa.u[7] = f2b(eb.w);
            bf8_t bv = *(const bf8_t*)(skv + (wave * 16 + lq) * 72 + ks * 32 + quad * 8);
            acc = __builtin_amdgcn_mfma_f32_16x16x32_bf16(pa.v, bv, acc, 0, 0, 0);
        }
        __syncthreads();
    }
    #pragma unroll
    for (int r = 0; r < 4; ++r) {
        int l = l0 + quad * 4 + r;
        attn_out[((size_t)b * SEQ + l) * D_MODEL + h * 64 + wave * 16 + lq] = f2b(acc[r]);
    }
}

// ---------------------------------------------------------------------------
// FC: Out = X(bf16) * W^T + bias + residual -> fp32. m97 structure:
// linear LDS + global_load_lds staging for A and B.
// ---------------------------------------------------------------------------
__global__ __launch_bounds__(256) void fc_mfma(
    const unsigned short* __restrict__ X, const unsigned short* __restrict__ W,
    const float* __restrict__ bias, const float* __restrict__ residual,
    float* __restrict__ Out)
{
    const int m0 = blockIdx.y * 128;
    const int n0 = blockIdx.x * 128;

    __shared__ alignas(16) unsigned short As[128 * 64];
    __shared__ alignas(16) unsigned short Bs[128 * 64];

    const int tid = threadIdx.x;
    const int wave = tid >> 6, lane = tid & 63;
    const int quad = lane >> 4, lq = lane & 15;
    const int wr = wave >> 1, wc = wave & 1;

    f4_t acc[4][4];
    #pragma unroll
    for (int i = 0; i < 4; ++i)
        #pragma unroll
        for (int j = 0; j < 4; ++j)
            #pragma unroll
            for (int r = 0; r < 4; ++r) acc[i][j][r] = 0.0f;

    for (int k0 = 0; k0 < D_MODEL; k0 += 64) {
        #pragma unroll
        for (int i = 0; i < 4; ++i) {
            int c = tid + 256 * i;
            int row = c >> 3, off = (c & 7) * 8;
            int lbase = ((tid & ~63) + 256 * i) * 8;     // wave-uniform, shorts
            GLOAD16(X + (size_t)(m0 + row) * D_MODEL + k0 + off, As + lbase);
            GLOAD16(W + (size_t)(n0 + row) * D_MODEL + k0 + off, Bs + lbase);
        }
        __syncthreads();
        #pragma unroll
        for (int ks = 0; ks < 2; ++ks) {
            bf8_t af[4], bfr[4];
            #pragma unroll
            for (int i = 0; i < 4; ++i)
                af[i] = *(const bf8_t*)(As + (wr * 64 + i * 16 + lq) * 64 + ks * 32 + quad * 8);
            #pragma unroll
            for (int j = 0; j < 4; ++j)
                bfr[j] = *(const bf8_t*)(Bs + (wc * 64 + j * 16 + lq) * 64 + ks * 32 + quad * 8);
            #pragma unroll
            for (int i = 0; i < 4; ++i)
                #pragma unroll
                for (int j = 0; j < 4; ++j)
                    acc[i][j] = __builtin_amdgcn_mfma_f32_16x16x32_bf16(af[i], bfr[j], acc[i][j], 0, 0, 0);
        }
        __syncthreads();
    }

    #pragma unroll
    for (int j = 0; j < 4; ++j) {
        int col = n0 + wc * 64 + j * 16 + lq;
        float bv_ = bias[col];
        #pragma unroll
        for (int i = 0; i < 4; ++i) {
            #pragma unroll
            for (int r = 0; r < 4; ++r) {
                int m = m0 + wr * 64 + i * 16 + quad * 4 + r;
                Out[(size_t)m * D_MODEL + col] =
                    acc[i][j][r] + bv_ + residual[(size_t)m * D_MODEL + col];
            }
        }
    }
}

// ---------------------------------------------------------------------------
// Kernel: LayerNorm over 768 per row -> d_out
// ---------------------------------------------------------------------------
__global__ __launch_bounds__(256) void ln_k(
    const float* __restrict__ X, const float* __restrict__ g,
    const float* __restrict__ bta, float* __restrict__ out)
{
    const int row = blockIdx.x;
    const float* x = X + (size_t)row * D_MODEL;
    const int tid = threadIdx.x;
    const int lane = tid & 63, wid = tid >> 6;
    __shared__ float s1[4], s2[4];

    float v0 = x[tid], v1 = x[tid + 256], v2 = x[tid + 512];
    float s = v0 + v1 + v2;
    float q = v0 * v0 + v1 * v1 + v2 * v2;
    #pragma unroll
    for (int o = 32; o > 0; o >>= 1) {
        s += __shfl_down(s, o, 64);
        q += __shfl_down(q, o, 64);
    }
    if (lane == 0) { s1[wid] = s; s2[wid] = q; }
    __syncthreads();
    const float sum = s1[0] + s1[1] + s1[2] + s1[3];
    const float sq  = s2[0] + s2[1] + s2[2] + s2[3];
    const float mu = sum * (1.0f / D_MODEL);
    const float var = sq * (1.0f / D_MODEL) - mu * mu;
    const float r = rsqrtf(var + 1e-5f);

    float* o = out + (size_t)row * D_MODEL;
    o[tid]       = (v0 - mu) * r * g[tid]       + bta[tid];
    o[tid + 256] = (v1 - mu) * r * g[tid + 256] + bta[tid + 256];
    o[tid + 512] = (v2 - mu) * r * g[tid + 512] + bta[tid + 512];
}

// ---------------------------------------------------------------------------
extern "C" void kernel_launch(void* const* d_in, const int* in_sizes, int n_in,
                              void* d_out, int out_size, void* d_ws, size_t ws_size,
                              hipStream_t stream)
{
    const float* q    = (const float*)d_in[0];
    const float* k    = (const float*)d_in[1];
    const float* v    = (const float*)d_in[2];
    const float* pl   = (const float*)d_in[3];
    const int*   mask = (const int*)d_in[4];
    const float* wq   = (const float*)d_in[5];
    const float* bq   = (const float*)d_in[6];
    const float* wk   = (const float*)d_in[7];
    const float* bk   = (const float*)d_in[8];
    const float* wv   = (const float*)d_in[9];
    const float* bv   = (const float*)d_in[10];
    const float* wfc  = (const float*)d_in[11];
    const float* bfc  = (const float*)d_in[12];
    const float* wloc = (const float*)d_in[13];
    const float* bloc = (const float*)d_in[14];
    const float* lng  = (const float*)d_in[15];
    const float* lnb  = (const float*)d_in[16];

    char* W8 = (char*)d_ws;
    const size_t SLOT = (size_t)PROJ_ELEMS * 2;            // 6291456 B per bf16 tensor
    unsigned short* qb   = (unsigned short*)(W8 + 0 * SLOT);
    unsigned short* kb   = (unsigned short*)(W8 + 1 * SLOT);
    unsigned short* vb   = (unsigned short*)(W8 + 2 * SLOT);
    unsigned short* qh   = (unsigned short*)(W8 + 3 * SLOT);
    unsigned short* kh   = (unsigned short*)(W8 + 4 * SLOT);
    unsigned short* vh   = (unsigned short*)(W8 + 5 * SLOT);   // dead after vtrans
    unsigned short* vT   = (unsigned short*)(W8 + 6 * SLOT);
    unsigned short* wqb  = (unsigned short*)(W8 + 7 * SLOT);
    unsigned short* wkb  = (unsigned short*)(W8 + 7 * SLOT + 1179648);
    unsigned short* wvb  = (unsigned short*)(W8 + 7 * SLOT + 2 * 1179648);
    unsigned short* wfcb = (unsigned short*)(W8 + 7 * SLOT + 3 * 1179648);
    // overlays (sources dead by the time these are written):
    unsigned short* attn_out = (unsigned short*)(W8 + 0 * SLOT); // over qb (dead after proj)
    float*          fc_out   = (float*)(W8 + 2 * SLOT);          // over vb+qh (dead)

    float* out   = (float*)d_out;                 // [b][l][768]
    float* fused = out + (size_t)PROJ_ELEMS;      // [h][b][l][t] fp32

    cvt_k<<<dim3(3072, 1, 3), 256, 0, stream>>>(q, k, v, v, qb, kb, vb, vb, PROJ_ELEMS);
    cvt_k<<<dim3(576, 1, 4), 256, 0, stream>>>(wq, wk, wv, wfc, wqb, wkb, wvb, wfcb,
                                               D_MODEL * D_MODEL);
    proj_mfma<<<dim3(6, 32, 3), 256, 0, stream>>>(qb, kb, vb, wqb, wkb, wvb,
                                                  bq, bk, bv, qh, kh, vh);
    vtrans<<<dim3(16, HB), 256, 0, stream>>>(vh, vT);
    attn_pv<<<dim3(3072), 256, 0, stream>>>(qh, kh, vT, pl, mask, wloc, bloc,
                                            fused, attn_out);
    fc_mfma<<<dim3(6, 32), 256, 0, stream>>>(attn_out, wfcb, bfc, q, fc_out);
    ln_k<<<dim3(BATCH * SEQ), 256, 0, stream>>>(fc_out, lng, lnb, out);
}

// Round 5
// 542.081 us; speedup vs baseline: 1.0651x; 1.0521x over previous
//
#include <hip/hip_runtime.h>
#include <hip/hip_bf16.h>
#include <stdint.h>

#define D_MODEL 768
#define N_HEAD 12
#define D_HEAD 64
#define BATCH 4
#define SEQ 1024
#define HB 48
#define PROJ_ELEMS (BATCH * SEQ * D_MODEL)   // 3145728

typedef __attribute__((ext_vector_type(8))) short bf8_t;   // 8 bf16 = one MFMA A/B frag
typedef __attribute__((ext_vector_type(4))) float f4_t;    // 4 fp32 = one MFMA C/D frag

__device__ inline unsigned short f2b(float f) {           // RNE float->bf16
    union { float f; unsigned u; } v; v.f = f;
    unsigned r = v.u + 0x7FFFu + ((v.u >> 16) & 1u);
    return (unsigned short)(r >> 16);
}

__device__ inline float b2f(unsigned short b) {           // bf16->fp32 (exact)
    union { unsigned u; float f; } v; v.u = (unsigned)b << 16;
    return v.f;
}

// async 16B global->LDS DMA (m97 pattern). lds base must be wave-uniform;
// HW adds lane*16. size must be a literal.
#define GLOAD16(gp, lp)                                                      \
    __builtin_amdgcn_global_load_lds(                                        \
        (const __attribute__((address_space(1))) void*)(gp),                 \
        (__attribute__((address_space(3))) void*)(lp), 16, 0, 0)

// ---------------------------------------------------------------------------
// fp32 -> bf16 bulk convert (z picks one of up to 4 tensors)
// ---------------------------------------------------------------------------
__global__ __launch_bounds__(256) void cvt_k(
    const float* __restrict__ s0, const float* __restrict__ s1,
    const float* __restrict__ s2, const float* __restrict__ s3,
    unsigned short* __restrict__ d0, unsigned short* __restrict__ d1,
    unsigned short* __restrict__ d2, unsigned short* __restrict__ d3, int n)
{
    const int z = blockIdx.z;
    const float* s = (z == 0) ? s0 : (z == 1) ? s1 : (z == 2) ? s2 : s3;
    unsigned short* d = (z == 0) ? d0 : (z == 1) ? d1 : (z == 2) ? d2 : d3;
    int i = (blockIdx.x * 256 + threadIdx.x) * 4;
    if (i >= n) return;
    float4 v = *(const float4*)(s + i);
    ushort4 o;
    o.x = f2b(v.x); o.y = f2b(v.y); o.z = f2b(v.z); o.w = f2b(v.w);
    *(ushort4*)(d + i) = o;
}

// ---------------------------------------------------------------------------
// QKV projection: Y = X * W^T + bias, bf16 MFMA, 128x128 tile, BK=64.
// m97 structure: linear LDS + global_load_lds dwordx4 staging (A and B).
// Output head-split bf16: out[((h*4+b)*1024 + l)*64 + dh]
// ---------------------------------------------------------------------------
__global__ __launch_bounds__(256) void proj_mfma(
    const unsigned short* __restrict__ qb, const unsigned short* __restrict__ kb,
    const unsigned short* __restrict__ vb,
    const unsigned short* __restrict__ wqb, const unsigned short* __restrict__ wkb,
    const unsigned short* __restrict__ wvb,
    const float* __restrict__ bq, const float* __restrict__ bk, const float* __restrict__ bv,
    unsigned short* __restrict__ qh, unsigned short* __restrict__ kh,
    unsigned short* __restrict__ vh)
{
    const int z = blockIdx.z;
    const unsigned short* X = (z == 0) ? qb : (z == 1) ? kb : vb;
    const unsigned short* W = (z == 0) ? wqb : (z == 1) ? wkb : wvb;
    const float* bias = (z == 0) ? bq : (z == 1) ? bk : bv;
    unsigned short* Out = (z == 0) ? qh : (z == 1) ? kh : vh;

    const int m0 = blockIdx.y * 128;
    const int n0 = blockIdx.x * 128;

    __shared__ alignas(16) unsigned short As[128 * 64];   // linear, DMA-staged
    __shared__ alignas(16) unsigned short Bs[128 * 64];

    const int tid = threadIdx.x;
    const int wave = tid >> 6, lane = tid & 63;
    const int quad = lane >> 4, lq = lane & 15;
    const int wr = wave >> 1, wc = wave & 1;   // wave's 64x64 quadrant

    f4_t acc[4][4];
    #pragma unroll
    for (int i = 0; i < 4; ++i)
        #pragma unroll
        for (int j = 0; j < 4; ++j)
            #pragma unroll
            for (int r = 0; r < 4; ++r) acc[i][j][r] = 0.0f;

    for (int k0 = 0; k0 < D_MODEL; k0 += 64) {
        #pragma unroll
        for (int i = 0; i < 4; ++i) {
            int c = tid + 256 * i;            // 1024 16B-chunks per tile
            int row = c >> 3, off = (c & 7) * 8;
            int lbase = ((tid & ~63) + 256 * i) * 8;     // wave-uniform, shorts
            GLOAD16(X + (size_t)(m0 + row) * D_MODEL + k0 + off, As + lbase);
            GLOAD16(W + (size_t)(n0 + row) * D_MODEL + k0 + off, Bs + lbase);
        }
        __syncthreads();
        #pragma unroll
        for (int ks = 0; ks < 2; ++ks) {
            bf8_t af[4], bfr[4];
            #pragma unroll
            for (int i = 0; i < 4; ++i)
                af[i] = *(const bf8_t*)(As + (wr * 64 + i * 16 + lq) * 64 + ks * 32 + quad * 8);
            #pragma unroll
            for (int j = 0; j < 4; ++j)
                bfr[j] = *(const bf8_t*)(Bs + (wc * 64 + j * 16 + lq) * 64 + ks * 32 + quad * 8);
            #pragma unroll
            for (int i = 0; i < 4; ++i)
                #pragma unroll
                for (int j = 0; j < 4; ++j)
                    acc[i][j] = __builtin_amdgcn_mfma_f32_16x16x32_bf16(af[i], bfr[j], acc[i][j], 0, 0, 0);
        }
        __syncthreads();
    }

    const int bb = m0 >> 10;
    #pragma unroll
    for (int j = 0; j < 4; ++j) {
        int col = n0 + wc * 64 + j * 16 + lq;
        float bv_ = bias[col];
        int h = col >> 6, dh = col & 63;
        #pragma unroll
        for (int i = 0; i < 4; ++i) {
            #pragma unroll
            for (int r = 0; r < 4; ++r) {
                int m = m0 + wr * 64 + i * 16 + quad * 4 + r;
                int l = m & 1023;
                Out[(((size_t)(h * BATCH + bb) * SEQ + l) << 6) + dh] = f2b(acc[i][j][r] + bv_);
            }
        }
    }
}

// ---------------------------------------------------------------------------
// Transpose V per (hb, t-tile): vT[hb][dh][t] from vh[hb][t][dh]
// ---------------------------------------------------------------------------
__global__ __launch_bounds__(256) void vtrans(
    const unsigned short* __restrict__ vh, unsigned short* __restrict__ vT)
{
    const int hb = blockIdx.y, tt = blockIdx.x;
    __shared__ alignas(16) unsigned short s[64 * 72];
    const int tid = threadIdx.x;
    #pragma unroll
    for (int i = 0; i < 2; ++i) {
        int c = tid + 256 * i;
        int t = c >> 3, off = (c & 7) * 8;
        *(bf8_t*)(s + t * 72 + off) =
            *(const bf8_t*)(vh + ((size_t)hb * SEQ + tt * 64 + t) * 64 + off);
    }
    __syncthreads();
    #pragma unroll
    for (int i = 0; i < 2; ++i) {
        int c = tid + 256 * i;
        int dh = c >> 3, toff = (c & 7) * 8;
        union { unsigned short u[8]; bf8_t v; } tmp;
        #pragma unroll
        for (int j = 0; j < 8; ++j) tmp.u[j] = s[(toff + j) * 72 + dh];
        *(bf8_t*)(vT + ((size_t)hb * 64 + dh) * SEQ + tt * 64 + toff) = tmp.v;
    }
}

// ---------------------------------------------------------------------------
// FUSED attention: per block = (head h, batch b, 16 l-rows).
// Pass 1: loop 16 t-tiles: QK MFMA + loc -> e; e stored BF16 in LDS
//         [16][1024] (33 KB vs 65.8 KB fp32 -> 3 blocks/CU instead of 2),
//         row sums accumulated fp32 in registers.
// Pass 2: loop 16 t-tiles: p = b2f(e)*invS, written ONCE to fused (fp32),
//         PV MFMA (P = f2b(p), same rounding point as before) -> attn_out.
// bf16 e-storage adds <=2^-9 rel err on fused p — far below the existing
// bf16-GEMM error that sets absmax (0.03125 = 1 bf16 ulp @ [4,8)).
// ---------------------------------------------------------------------------
__global__ __launch_bounds__(256) void attn_pv(
    const unsigned short* __restrict__ qh, const unsigned short* __restrict__ kh,
    const unsigned short* __restrict__ vT,
    const float* __restrict__ pl, const int* __restrict__ mask,
    const float* __restrict__ wloc, const float* __restrict__ bloc,
    float* __restrict__ fused, unsigned short* __restrict__ attn_out)
{
    const int orig = blockIdx.x;                       // 0..3071
    const int swz  = (orig & 7) * 384 + (orig >> 3);   // bijective (3072 = 8*384)
    const int h  = swz % 12;
    const int g  = swz / 12;                           // 0..255 = (b, l-tile)
    const int b  = g >> 6;
    const int l0 = (g & 63) * 16;
    const int hb = h * BATCH + b;

    __shared__ alignas(16) unsigned short eS[16 * 1032];  // bf16 e, 16B-aligned rows
    __shared__ alignas(16) unsigned short sq[16 * 72];
    __shared__ alignas(16) unsigned short skv[64 * 72];   // K (pass1) / V^T (pass2)
    __shared__ float rsum[4][16];
    __shared__ float sinv[16];

    const int tid = threadIdx.x;
    const int wave = tid >> 6, lane = tid & 63;
    const int quad = lane >> 4, lq = lane & 15;

    // stage Q once (16 rows x 8 chunks); first in-loop barrier orders it
    if (tid < 128) {
        int row = tid >> 3, off = (tid & 7) * 8;
        *(bf8_t*)(sq + row * 72 + off) =
            *(const bf8_t*)(qh + (((size_t)hb * SEQ) + l0 + row) * 64 + off);
    }

    const float wl0 = wloc[h * 5 + 0], wl1 = wloc[h * 5 + 1], wl2 = wloc[h * 5 + 2];
    const float wl3 = wloc[h * 5 + 3], wl4 = wloc[h * 5 + 4];
    const float bl = bloc[h];

    // ---------------- pass 1: e (bf16 in LDS) + fp32 row sums ----------------
    float sr[4] = {0.f, 0.f, 0.f, 0.f};
    for (int tt = 0; tt < 16; ++tt) {
        #pragma unroll
        for (int i = 0; i < 2; ++i) {          // stage K-tile: 64 rows x 8 chunks
            int c = tid + 256 * i;
            int r2 = c >> 3, o2 = (c & 7) * 8;
            *(bf8_t*)(skv + r2 * 72 + o2) =
                *(const bf8_t*)(kh + (((size_t)hb * SEQ) + tt * 64 + r2) * 64 + o2);
        }
        const int t = tt * 64 + wave * 16 + lq;
        const int mk = mask[b * SEQ + t];
        float p5[4][5];
        #pragma unroll
        for (int r = 0; r < 4; ++r) {
            const float* pp = pl + (((size_t)(b * SEQ + l0 + quad * 4 + r) * SEQ) + t) * 5;
            #pragma unroll
            for (int j = 0; j < 5; ++j) p5[r][j] = pp[j];
        }
        __syncthreads();

        bf8_t a0 = *(const bf8_t*)(sq + lq * 72 + quad * 8);
        bf8_t a1 = *(const bf8_t*)(sq + lq * 72 + 32 + quad * 8);
        bf8_t b0 = *(const bf8_t*)(skv + (wave * 16 + lq) * 72 + quad * 8);
        bf8_t b1 = *(const bf8_t*)(skv + (wave * 16 + lq) * 72 + 32 + quad * 8);
        f4_t qk = {0.f, 0.f, 0.f, 0.f};
        qk = __builtin_amdgcn_mfma_f32_16x16x32_bf16(a0, b0, qk, 0, 0, 0);
        qk = __builtin_amdgcn_mfma_f32_16x16x32_bf16(a1, b1, qk, 0, 0, 0);

        #pragma unroll
        for (int r = 0; r < 4; ++r) {
            int ll = quad * 4 + r;
            float loc = fmaf(wl0, p5[r][0], fmaf(wl1, p5[r][1], fmaf(wl2, p5[r][2],
                        fmaf(wl3, p5[r][3], fmaf(wl4, p5[r][4], bl)))));
            float e = mk ? 0.0f : fmaxf(loc, 1e-6f) * __expf(0.125f * qk[r]);
            eS[ll * 1032 + t] = f2b(e);
            sr[r] += e;
        }
        __syncthreads();
    }
    // wave's 16-t partial sums -> block row sums -> invS
    #pragma unroll
    for (int o = 1; o < 16; o <<= 1) {
        sr[0] += __shfl_xor(sr[0], o, 64);
        sr[1] += __shfl_xor(sr[1], o, 64);
        sr[2] += __shfl_xor(sr[2], o, 64);
        sr[3] += __shfl_xor(sr[3], o, 64);
    }
    if (lq == 0) {
        #pragma unroll
        for (int r = 0; r < 4; ++r) rsum[wave][quad * 4 + r] = sr[r];
    }
    __syncthreads();
    if (tid < 16)
        sinv[tid] = 1.0f / (rsum[0][tid] + rsum[1][tid] + rsum[2][tid] + rsum[3][tid]);
    __syncthreads();

    // ---------------- pass 2: fused write + PV ----------------
    const float inv = sinv[lq];
    f4_t acc = {0.f, 0.f, 0.f, 0.f};           // wave's 16l x 16dh tile
    for (int tt = 0; tt < 16; ++tt) {
        #pragma unroll
        for (int i = 0; i < 2; ++i) {          // stage V^T-tile: 64 dh x 8 chunks
            int c = tid + 256 * i;
            int row = c >> 3, off = (c & 7) * 8;
            *(bf8_t*)(skv + row * 72 + off) =
                *(const bf8_t*)(vT + ((size_t)hb * 64 + row) * SEQ + tt * 64 + off);
        }
        __syncthreads();
        #pragma unroll
        for (int ks = 0; ks < 2; ++ks) {
            union { unsigned short u[8]; bf8_t v; } ev;
            ev.v = *(const bf8_t*)(eS + lq * 1032 + tt * 64 + ks * 32 + quad * 8);
            float p[8];
            #pragma unroll
            for (int j = 0; j < 8; ++j) p[j] = b2f(ev.u[j]) * inv;
            if ((tt & 3) == wave) {            // rotating duty wave writes fused
                float* fp = fused + ((size_t)hb * SEQ + l0 + lq) * SEQ
                                  + tt * 64 + ks * 32 + quad * 8;
                float4 fa = {p[0], p[1], p[2], p[3]};
                float4 fb = {p[4], p[5], p[6], p[7]};
                *(float4*)fp = fa;
                *(float4*)(fp + 4) = fb;
            }
            union { unsigned short u[8]; bf8_t v; } pa;
            #pragma unroll
            for (int j = 0; j < 8; ++j) pa.u[j] = f2b(p[j]);
            bf8_t bv = *(const bf8_t*)(skv + (wave * 16 + lq) * 72 + ks * 32 + quad * 8);
            acc = __builtin_amdgcn_mfma_f32_16x16x32_bf16(pa.v, bv, acc, 0, 0, 0);
        }
        __syncthreads();
    }
    #pragma unroll
    for (int r = 0; r < 4; ++r) {
        int l = l0 + quad * 4 + r;
        attn_out[((size_t)b * SEQ + l) * D_MODEL + h * 64 + wave * 16 + lq] = f2b(acc[r]);
    }
}

// ---------------------------------------------------------------------------
// FC: Out = X(bf16) * W^T + bias + residual -> fp32. m97 structure:
// linear LDS + global_load_lds staging for A and B.
// ---------------------------------------------------------------------------
__global__ __launch_bounds__(256) void fc_mfma(
    const unsigned short* __restrict__ X, const unsigned short* __restrict__ W,
    const float* __restrict__ bias, const float* __restrict__ residual,
    float* __restrict__ Out)
{
    const int m0 = blockIdx.y * 128;
    const int n0 = blockIdx.x * 128;

    __shared__ alignas(16) unsigned short As[128 * 64];
    __shared__ alignas(16) unsigned short Bs[128 * 64];

    const int tid = threadIdx.x;
    const int wave = tid >> 6, lane = tid & 63;
    const int quad = lane >> 4, lq = lane & 15;
    const int wr = wave >> 1, wc = wave & 1;

    f4_t acc[4][4];
    #pragma unroll
    for (int i = 0; i < 4; ++i)
        #pragma unroll
        for (int j = 0; j < 4; ++j)
            #pragma unroll
            for (int r = 0; r < 4; ++r) acc[i][j][r] = 0.0f;

    for (int k0 = 0; k0 < D_MODEL; k0 += 64) {
        #pragma unroll
        for (int i = 0; i < 4; ++i) {
            int c = tid + 256 * i;
            int row = c >> 3, off = (c & 7) * 8;
            int lbase = ((tid & ~63) + 256 * i) * 8;     // wave-uniform, shorts
            GLOAD16(X + (size_t)(m0 + row) * D_MODEL + k0 + off, As + lbase);
            GLOAD16(W + (size_t)(n0 + row) * D_MODEL + k0 + off, Bs + lbase);
        }
        __syncthreads();
        #pragma unroll
        for (int ks = 0; ks < 2; ++ks) {
            bf8_t af[4], bfr[4];
            #pragma unroll
            for (int i = 0; i < 4; ++i)
                af[i] = *(const bf8_t*)(As + (wr * 64 + i * 16 + lq) * 64 + ks * 32 + quad * 8);
            #pragma unroll
            for (int j = 0; j < 4; ++j)
                bfr[j] = *(const bf8_t*)(Bs + (wc * 64 + j * 16 + lq) * 64 + ks * 32 + quad * 8);
            #pragma unroll
            for (int i = 0; i < 4; ++i)
                #pragma unroll
                for (int j = 0; j < 4; ++j)
                    acc[i][j] = __builtin_amdgcn_mfma_f32_16x16x32_bf16(af[i], bfr[j], acc[i][j], 0, 0, 0);
        }
        __syncthreads();
    }

    #pragma unroll
    for (int j = 0; j < 4; ++j) {
        int col = n0 + wc * 64 + j * 16 + lq;
        float bv_ = bias[col];
        #pragma unroll
        for (int i = 0; i < 4; ++i) {
            #pragma unroll
            for (int r = 0; r < 4; ++r) {
                int m = m0 + wr * 64 + i * 16 + quad * 4 + r;
                Out[(size_t)m * D_MODEL + col] =
                    acc[i][j][r] + bv_ + residual[(size_t)m * D_MODEL + col];
            }
        }
    }
}

// ---------------------------------------------------------------------------
// Kernel: LayerNorm over 768 per row -> d_out
// ---------------------------------------------------------------------------
__global__ __launch_bounds__(256) void ln_k(
    const float* __restrict__ X, const float* __restrict__ g,
    const float* __restrict__ bta, float* __restrict__ out)
{
    const int row = blockIdx.x;
    const float* x = X + (size_t)row * D_MODEL;
    const int tid = threadIdx.x;
    const int lane = tid & 63, wid = tid >> 6;
    __shared__ float s1[4], s2[4];

    float v0 = x[tid], v1 = x[tid + 256], v2 = x[tid + 512];
    float s = v0 + v1 + v2;
    float q = v0 * v0 + v1 * v1 + v2 * v2;
    #pragma unroll
    for (int o = 32; o > 0; o >>= 1) {
        s += __shfl_down(s, o, 64);
        q += __shfl_down(q, o, 64);
    }
    if (lane == 0) { s1[wid] = s; s2[wid] = q; }
    __syncthreads();
    const float sum = s1[0] + s1[1] + s1[2] + s1[3];
    const float sq  = s2[0] + s2[1] + s2[2] + s2[3];
    const float mu = sum * (1.0f / D_MODEL);
    const float var = sq * (1.0f / D_MODEL) - mu * mu;
    const float r = rsqrtf(var + 1e-5f);

    float* o = out + (size_t)row * D_MODEL;
    o[tid]       = (v0 - mu) * r * g[tid]       + bta[tid];
    o[tid + 256] = (v1 - mu) * r * g[tid + 256] + bta[tid + 256];
    o[tid + 512] = (v2 - mu) * r * g[tid + 512] + bta[tid + 512];
}

// ---------------------------------------------------------------------------
extern "C" void kernel_launch(void* const* d_in, const int* in_sizes, int n_in,
                              void* d_out, int out_size, void* d_ws, size_t ws_size,
                              hipStream_t stream)
{
    const float* q    = (const float*)d_in[0];
    const float* k    = (const float*)d_in[1];
    const float* v    = (const float*)d_in[2];
    const float* pl   = (const float*)d_in[3];
    const int*   mask = (const int*)d_in[4];
    const float* wq   = (const float*)d_in[5];
    const float* bq   = (const float*)d_in[6];
    const float* wk   = (const float*)d_in[7];
    const float* bk   = (const float*)d_in[8];
    const float* wv   = (const float*)d_in[9];
    const float* bv   = (const float*)d_in[10];
    const float* wfc  = (const float*)d_in[11];
    const float* bfc  = (const float*)d_in[12];
    const float* wloc = (const float*)d_in[13];
    const float* bloc = (const float*)d_in[14];
    const float* lng  = (const float*)d_in[15];
    const float* lnb  = (const float*)d_in[16];

    char* W8 = (char*)d_ws;
    const size_t SLOT = (size_t)PROJ_ELEMS * 2;            // 6291456 B per bf16 tensor
    unsigned short* qb   = (unsigned short*)(W8 + 0 * SLOT);
    unsigned short* kb   = (unsigned short*)(W8 + 1 * SLOT);
    unsigned short* vb   = (unsigned short*)(W8 + 2 * SLOT);
    unsigned short* qh   = (unsigned short*)(W8 + 3 * SLOT);
    unsigned short* kh   = (unsigned short*)(W8 + 4 * SLOT);
    unsigned short* vh   = (unsigned short*)(W8 + 5 * SLOT);   // dead after vtrans
    unsigned short* vT   = (unsigned short*)(W8 + 6 * SLOT);
    unsigned short* wqb  = (unsigned short*)(W8 + 7 * SLOT);
    unsigned short* wkb  = (unsigned short*)(W8 + 7 * SLOT + 1179648);
    unsigned short* wvb  = (unsigned short*)(W8 + 7 * SLOT + 2 * 1179648);
    unsigned short* wfcb = (unsigned short*)(W8 + 7 * SLOT + 3 * 1179648);
    // overlays (sources dead by the time these are written):
    unsigned short* attn_out = (unsigned short*)(W8 + 0 * SLOT); // over qb (dead after proj)
    float*          fc_out   = (float*)(W8 + 2 * SLOT);          // over vb+qh (dead)

    float* out   = (float*)d_out;                 // [b][l][768]
    float* fused = out + (size_t)PROJ_ELEMS;      // [h][b][l][t] fp32

    cvt_k<<<dim3(3072, 1, 3), 256, 0, stream>>>(q, k, v, v, qb, kb, vb, vb, PROJ_ELEMS);
    cvt_k<<<dim3(576, 1, 4), 256, 0, stream>>>(wq, wk, wv, wfc, wqb, wkb, wvb, wfcb,
                                               D_MODEL * D_MODEL);
    proj_mfma<<<dim3(6, 32, 3), 256, 0, stream>>>(qb, kb, vb, wqb, wkb, wvb,
                                                  bq, bk, bv, qh, kh, vh);
    vtrans<<<dim3(16, HB), 256, 0, stream>>>(vh, vT);
    attn_pv<<<dim3(3072), 256, 0, stream>>>(qh, kh, vT, pl, mask, wloc, bloc,
                                            fused, attn_out);
    fc_mfma<<<dim3(6, 32), 256, 0, stream>>>(attn_out, wfcb, bfc, q, fc_out);
    ln_k<<<dim3(BATCH * SEQ), 256, 0, stream>>>(fc_out, lng, lnb, out);
}